// Round 2
// 173.729 us; speedup vs baseline: 1.0137x; 1.0137x over previous
//
#include <hip/hip_runtime.h>
#include <math.h>

#define B 2
#define C 256
#define H 128
#define W 128
#define H2 256
#define W2 256
#define CPT 16  // channels per thread in main kernel
#define TW 16   // weights kernel tile width

typedef float vfloat4 __attribute__((ext_vector_type(4)));  // native vec for nontemporal builtin

__device__ __forceinline__ float frcp(float x) { return __builtin_amdgcn_rcpf(x); }
__device__ __forceinline__ float fast_tanh(float x) {
    float e = __expf(2.0f * x);
    return 1.0f - 2.0f * frcp(e + 1.0f);
}

__device__ __forceinline__ void nt_store4(float* p, const float4& v) {
    vfloat4 t; t.x = v.x; t.y = v.y; t.z = v.z; t.w = v.w;
    __builtin_nontemporal_store(t, (vfloat4*)p);
}

// ---------------- Kernel 1: channel mean ----------------
// One block per (b,h) row. 1024 threads = 32 channel-groups x 32 float4-columns.
__global__ __launch_bounds__(1024) void mean_kernel(const float* __restrict__ x,
                                                    float* __restrict__ mean) {
    int bh = blockIdx.x;            // 0 .. B*H-1
    int b = bh / H, h = bh % H;
    int tid = threadIdx.x;
    int g  = tid >> 5;              // channel group 0..31
    int w4 = tid & 31;              // float4 column 0..31

    const float4* xb = (const float4*)x + (size_t)b * C * (H * W / 4)
                       + (size_t)h * (W / 4) + w4;
    const size_t cstride = H * W / 4;

    float4 acc = make_float4(0.f, 0.f, 0.f, 0.f);
    #pragma unroll
    for (int i = 0; i < C / 32; ++i) {
        float4 v = xb[(size_t)(g * (C / 32) + i) * cstride];
        acc.x += v.x; acc.y += v.y; acc.z += v.z; acc.w += v.w;
    }

    __shared__ float4 sm[1024];
    sm[tid] = acc;
    __syncthreads();
    for (int s = 16; s >= 1; s >>= 1) {
        if (g < s) {
            float4 o = sm[tid + s * 32];
            acc.x += o.x; acc.y += o.y; acc.z += o.z; acc.w += o.w;
            sm[tid] = acc;
        }
        __syncthreads();
    }
    if (g == 0) {
        const float inv = 1.0f / C;
        float4 m = make_float4(acc.x * inv, acc.y * inv, acc.z * inv, acc.w * inv);
        ((float4*)mean)[(size_t)bh * (W / 4) + w4] = m;
    }
}

// ---------------- Kernel 2: softmax weights ----------------
// Block = 16x16 output pixels. Mean tile (10x10 + zero halo) and conv weights
// staged in LDS; fast transcendentals (v_rcp/v_exp) in the hot path.
__global__ __launch_bounds__(256) void weights_kernel(const float* __restrict__ mean,
                                                      const float* __restrict__ Woff,
                                                      const float* __restrict__ boff,
                                                      float* __restrict__ Kw) {
    __shared__ float sm[10][12];
    __shared__ float sW[50];
    __shared__ float sb[2];

    int b  = blockIdx.z;
    int x0 = blockIdx.x * TW;
    int y0 = blockIdx.y * TW;
    int h0 = y0 >> 1, w0 = x0 >> 1;
    int tid = threadIdx.x;

    if (tid < 100) {
        int lh = tid / 10, lw = tid % 10;
        int hh = h0 - 1 + lh, ww = w0 - 1 + lw;
        sm[lh][lw] = (hh >= 0 && hh < H && ww >= 0 && ww < W)
                         ? mean[(size_t)b * H * W + hh * W + ww] : 0.f;
    }
    if (tid >= 128 && tid < 178) sW[tid - 128] = Woff[tid - 128];
    if (tid >= 192 && tid < 194) sb[tid - 192] = boff[tid - 192];
    __syncthreads();

    int tx = tid & 15, ty = tid >> 4;
    int y = y0 + ty, x = x0 + tx;

    float off0 = 0.f, off1 = 0.f;
    #pragma unroll
    for (int u = 0; u < 5; ++u) {
        int lh = ((y + u - 2) >> 1) - (h0 - 1);
        #pragma unroll
        for (int v = 0; v < 5; ++v) {
            int lw = ((x + v - 2) >> 1) - (w0 - 1);
            float m = sm[lh][lw];
            off0 += m * sW[u * 5 + v];
            off1 += m * sW[25 + u * 5 + v];
        }
    }
    float s0 = fast_tanh(off0 + sb[0]) * 0.25f + ((x & 1) ? 0.25f : -0.25f);
    float s1 = fast_tanh(off1 + sb[1]) * 0.25f + ((y & 1) ? 0.25f : -0.25f);

    int lhc = (ty >> 1) + 1;
    int lwc = (tx >> 1) + 1;
    float mc = sm[lhc][lwc];

    float lg[9];
    float mx = -1e30f;
    #pragma unroll
    for (int k = 0; k < 9; ++k) {
        int di = k / 3 - 1, dj = k % 3 - 1;
        float pm = sm[lhc + di][lwc + dj];
        float g = pm - mc;
        float grad = frcp(g * g + 1.0f);
        float d0 = s0 - (float)dj;
        float d1 = s1 - (float)di;
        float kern = frcp(d0 * d0 + d1 * d1 + 0.2f);
        float l = grad * kern;
        lg[k] = l;
        mx = fmaxf(mx, l);
    }
    float sum = 0.f;
    #pragma unroll
    for (int k = 0; k < 9; ++k) { lg[k] = __expf(lg[k] - mx); sum += lg[k]; }
    float inv = frcp(sum);

    float* o = Kw + (size_t)b * 9 * (H2 * W2) + (size_t)y * W2 + x;
    #pragma unroll
    for (int k = 0; k < 9; ++k) o[(size_t)k * (H2 * W2)] = lg[k] * inv;
}

// ---------------- Kernel 3: CARAFE apply (v3) ----------------
// Thread = (b, 16-ch group, h, w2) with w2 in 0..63; wave spans one full input
// row (64 x float2 = 128 cols). Per channel: 3 coalesced float2 loads (rows
// h-1,h,h+1), halo columns via __shfl from neighbor lanes, 72 FMAs, 2 float4
// nontemporal stores. ALL boundary handling is folded into a one-time zeroing
// of the affected Kw weight components, so the channel loop is branch-free.
// (Clamped-row loads fetch real, finite x data that lands on zeroed weights.)
__global__ __launch_bounds__(256) void carafe_kernel(const float* __restrict__ x,
                                                     const float* __restrict__ Kw,
                                                     float* __restrict__ out) {
    int idx = blockIdx.x * blockDim.x + threadIdx.x;
    int w2 = idx & 63;              // output cols 4*w2 .. 4*w2+3
    int h  = (idx >> 6) & (H - 1);
    int cg = (idx >> 13) & (C / CPT - 1);
    int b  = idx >> 17;

    int x0 = 4 * w2;
    int y0 = 2 * h;

    // 18 float4 weights: rows y0,y0+1, cols x0..x0+3, for the 9 taps
    const float* kb = Kw + (size_t)b * 9 * (H2 * W2) + (size_t)y0 * W2 + x0;
    float4 wk[2][9];
    #pragma unroll
    for (int k = 0; k < 9; ++k) {
        wk[0][k] = *(const float4*)(kb + (size_t)k * (H2 * W2));
        wk[1][k] = *(const float4*)(kb + (size_t)k * (H2 * W2) + W2);
    }

    // one-time boundary weight zeroing:
    //  h edges kill whole tap-rows; w edges kill only the lane-edge components
    //  (.x,.y belong to parent col 2*w2; .z,.w to parent col 2*w2+1)
    float rm0 = (h == 0)     ? 0.f : 1.f;   // tap row di=-1
    float rm2 = (h == H - 1) ? 0.f : 1.f;   // tap row di=+1
    float cl  = (w2 == 0)    ? 0.f : 1.f;   // dj=-1 taps of parent 0
    float cr  = (w2 == 63)   ? 0.f : 1.f;   // dj=+1 taps of parent 127
    #pragma unroll
    for (int pp = 0; pp < 2; ++pp)
        #pragma unroll
        for (int k = 0; k < 9; ++k) {
            int ki = k / 3, kj = k % 3;
            float r  = (ki == 0) ? rm0 : ((ki == 2) ? rm2 : 1.f);
            float ma = (kj == 0) ? r * cl : r;
            float mb = (kj == 2) ? r * cr : r;
            wk[pp][k].x *= ma; wk[pp][k].y *= ma;
            wk[pp][k].z *= mb; wk[pp][k].w *= mb;
        }

    int r0 = (h == 0) ? 0 : h - 1;          // clamped: garbage x lands on 0-weights
    int r2 = (h == H - 1) ? H - 1 : h + 1;

    const float* xc = x + (size_t)(b * C + cg * CPT) * (H * W);
    const float2* row0 = (const float2*)(xc + (size_t)r0 * W) + w2;
    const float2* row1 = (const float2*)(xc + (size_t)h  * W) + w2;
    const float2* row2 = (const float2*)(xc + (size_t)r2 * W) + w2;

    float* ob = out + (size_t)(b * C + cg * CPT) * (H2 * W2)
                    + (size_t)y0 * W2 + x0;

    #pragma unroll 2
    for (int cc = 0; cc < CPT; ++cc) {
        float2 v0 = row0[0];
        float2 v1 = row1[0];
        float2 v2 = row2[0];

        // e[r][j] = input col (2*w2 - 1 + j) of patch row r
        float e[3][4];
        e[0][1] = v0.x; e[0][2] = v0.y;
        e[1][1] = v1.x; e[1][2] = v1.y;
        e[2][1] = v2.x; e[2][2] = v2.y;
        e[0][0] = __shfl_up(v0.y, 1);   e[0][3] = __shfl_down(v0.x, 1);
        e[1][0] = __shfl_up(v1.y, 1);   e[1][3] = __shfl_down(v1.x, 1);
        e[2][0] = __shfl_up(v2.y, 1);   e[2][3] = __shfl_down(v2.x, 1);

        float4 a0 = make_float4(0.f, 0.f, 0.f, 0.f);
        float4 a1 = make_float4(0.f, 0.f, 0.f, 0.f);
        #pragma unroll
        for (int k = 0; k < 9; ++k) {
            int ki = k / 3, kj = k % 3;
            float pa = e[ki][kj];        // taps of parent col 2*w2
            float pb = e[ki][kj + 1];    // taps of parent col 2*w2+1
            a0.x += wk[0][k].x * pa; a0.y += wk[0][k].y * pa;
            a0.z += wk[0][k].z * pb; a0.w += wk[0][k].w * pb;
            a1.x += wk[1][k].x * pa; a1.y += wk[1][k].y * pa;
            a1.z += wk[1][k].z * pb; a1.w += wk[1][k].w * pb;
        }
        nt_store4(ob, a0);
        nt_store4(ob + W2, a1);

        row0 = (const float2*)((const float*)row0 + H * W);
        row1 = (const float2*)((const float*)row1 + H * W);
        row2 = (const float2*)((const float*)row2 + H * W);
        ob += (size_t)H2 * W2;
    }
}

extern "C" void kernel_launch(void* const* d_in, const int* in_sizes, int n_in,
                              void* d_out, int out_size, void* d_ws, size_t ws_size,
                              hipStream_t stream) {
    const float* x    = (const float*)d_in[0];
    const float* Woff = (const float*)d_in[1];
    const float* boff = (const float*)d_in[2];
    float* out = (float*)d_out;

    float* mean = (float*)d_ws;                 // B*H*W floats      (128 KiB)
    float* Kw   = mean + (size_t)B * H * W;     // B*9*H2*W2 floats  (4.5 MiB)

    mean_kernel<<<B * H, 1024, 0, stream>>>(x, mean);

    dim3 wgrid(W2 / TW, H2 / TW, B);
    weights_kernel<<<wgrid, 256, 0, stream>>>(mean, Woff, boff, Kw);

    int mt = B * (C / CPT) * H * (W / 2);       // 262,144 threads
    carafe_kernel<<<mt / 256, 256, 0, stream>>>(x, Kw, out);
}

// Round 3
// 173.217 us; speedup vs baseline: 1.0167x; 1.0030x over previous
//
#include <hip/hip_runtime.h>
#include <math.h>

#define B 2
#define C 256
#define H 128
#define W 128
#define H2 256
#define W2 256
#define CPT 16  // channels per thread in fused kernel

typedef float vfloat4 __attribute__((ext_vector_type(4)));  // native vec for nontemporal builtin

__device__ __forceinline__ float frcp(float x) { return __builtin_amdgcn_rcpf(x); }
__device__ __forceinline__ float fast_tanh(float x) {
    float e = __expf(2.0f * x);
    return 1.0f - 2.0f * frcp(e + 1.0f);
}
__device__ __forceinline__ void nt_store4(float* p, const float4& v) {
    vfloat4 t; t.x = v.x; t.y = v.y; t.z = v.z; t.w = v.w;
    __builtin_nontemporal_store(t, (vfloat4*)p);
}

// ---------------- Kernel 1: channel mean ----------------
// One block per (b,h) row. 1024 threads = 32 channel-groups x 32 float4-columns.
__global__ __launch_bounds__(1024) void mean_kernel(const float* __restrict__ x,
                                                    float* __restrict__ mean) {
    int bh = blockIdx.x;            // 0 .. B*H-1
    int b = bh / H, h = bh % H;
    int tid = threadIdx.x;
    int g  = tid >> 5;              // channel group 0..31
    int w4 = tid & 31;              // float4 column 0..31

    const float4* xb = (const float4*)x + (size_t)b * C * (H * W / 4)
                       + (size_t)h * (W / 4) + w4;
    const size_t cstride = H * W / 4;

    float4 acc = make_float4(0.f, 0.f, 0.f, 0.f);
    #pragma unroll
    for (int i = 0; i < C / 32; ++i) {
        float4 v = xb[(size_t)(g * (C / 32) + i) * cstride];
        acc.x += v.x; acc.y += v.y; acc.z += v.z; acc.w += v.w;
    }

    __shared__ float4 sm[1024];
    sm[tid] = acc;
    __syncthreads();
    for (int s = 16; s >= 1; s >>= 1) {
        if (g < s) {
            float4 o = sm[tid + s * 32];
            acc.x += o.x; acc.y += o.y; acc.z += o.z; acc.w += o.w;
            sm[tid] = acc;
        }
        __syncthreads();
    }
    if (g == 0) {
        const float inv = 1.0f / C;
        float4 m = make_float4(acc.x * inv, acc.y * inv, acc.z * inv, acc.w * inv);
        ((float4*)mean)[(size_t)bh * (W / 4) + w4] = m;
    }
}

// ---------------- Kernel 2: fused weights + CARAFE apply ----------------
// Thread = (b, 16-ch group, h, w2); wave spans one full input row (64 float2).
// Phase 1: load 3x4 mean halo (3 float2 loads + 6 shfl, zero-masked at image
//   edges = conv zero-pad semantics), then compute all 72 softmax weights for
//   this thread's 2x4 output pixels ENTIRELY in registers (all indices static
//   after unroll). Out-of-image x-taps are folded into the weights as zeros.
// Phase 2: branch-free channel loop — 3 coalesced float2 x-loads, halo via
//   shfl, 72 FMAs, 2 float4 nontemporal stores per channel.
// Eliminates the separate weights kernel, the 4.7 MB Kw workspace round-trip,
// and 18 float4 Kw loads per thread.
__global__ __launch_bounds__(256) void carafe_fused(const float* __restrict__ x,
                                                    const float* __restrict__ mean,
                                                    const float* __restrict__ Woff,
                                                    const float* __restrict__ boff,
                                                    float* __restrict__ out) {
    __shared__ float sW[50];
    __shared__ float sb[2];
    int tid = threadIdx.x;
    if (tid < 50) sW[tid] = Woff[tid];
    else if (tid < 52) sb[tid - 50] = boff[tid - 50];
    __syncthreads();

    int idx = blockIdx.x * blockDim.x + tid;
    int w2 = idx & 63;              // lane id; output cols 4*w2 .. 4*w2+3
    int h  = (idx >> 6) & (H - 1);
    int cg = (idx >> 13) & (C / CPT - 1);
    int b  = idx >> 17;

    int r0 = (h == 0) ? 0 : h - 1;          // clamped row addrs (garbage x 0-weight)
    int r2 = (h == H - 1) ? H - 1 : h + 1;
    float rm0 = (h == 0)      ? 0.f : 1.f;  // tap row di=-1 invalid
    float rm2 = (h == H - 1)  ? 0.f : 1.f;  // tap row di=+1 invalid
    float cl  = (w2 == 0)     ? 0.f : 1.f;  // dj=-1 taps of parent col 0
    float cr  = (w2 == 63)    ? 0.f : 1.f;  // dj=+1 taps of parent col 127

    // ---- Phase 1: mean halo + in-register weight computation ----
    const float* mb = mean + (size_t)b * H * W;
    float2 u0 = ((const float2*)(mb + (size_t)r0 * W))[w2];
    float2 u1 = ((const float2*)(mb + (size_t)h  * W))[w2];
    float2 u2 = ((const float2*)(mb + (size_t)r2 * W))[w2];

    // m[r][c] = mean[h-1+r][2*w2-1+c], zero outside the image (pad semantics)
    float m[3][4];
    m[0][1] = u0.x; m[0][2] = u0.y;
    m[1][1] = u1.x; m[1][2] = u1.y;
    m[2][1] = u2.x; m[2][2] = u2.y;
    m[0][0] = __shfl_up(u0.y, 1);  m[0][3] = __shfl_down(u0.x, 1);
    m[1][0] = __shfl_up(u1.y, 1);  m[1][3] = __shfl_down(u1.x, 1);
    m[2][0] = __shfl_up(u2.y, 1);  m[2][3] = __shfl_down(u2.x, 1);
    #pragma unroll
    for (int c = 0; c < 4; ++c) { m[0][c] *= rm0; m[2][c] *= rm2; }
    #pragma unroll
    for (int r = 0; r < 3; ++r) { m[r][0] *= cl; m[r][3] *= cr; }

    // wgt[pp][k][j]: weight of tap k for output pixel (2h+pp, 4*w2+j),
    // boundary-masked. All indices compile-time static after unroll.
    float wgt[2][9][4];
    #pragma unroll
    for (int pp = 0; pp < 2; ++pp) {
        #pragma unroll
        for (int j = 0; j < 4; ++j) {
            // 5x5 conv on nearest-up2(mean) at output pixel (y,x)=(2h+pp,4w2+j):
            // mean_up[y+u-2][x+v-2] -> m[((pp+u-2)>>1)+1][((j+v-2)>>1)+1]
            float off0 = 0.f, off1 = 0.f;
            #pragma unroll
            for (int u = 0; u < 5; ++u) {
                const int rr = ((pp + u - 2) >> 1) + 1;   // folds to 0..2
                #pragma unroll
                for (int v = 0; v < 5; ++v) {
                    const int cc = ((j + v - 2) >> 1) + 1; // folds to 0..3
                    float mm = m[rr][cc];
                    off0 += mm * sW[u * 5 + v];
                    off1 += mm * sW[25 + u * 5 + v];
                }
            }
            float s0 = fast_tanh(off0 + sb[0]) * 0.25f + ((j & 1) ? 0.25f : -0.25f);
            float s1 = fast_tanh(off1 + sb[1]) * 0.25f + (pp ? 0.25f : -0.25f);

            const int jc = 1 + (j >> 1);    // parent col of this pixel within m
            float mc = m[1][jc];

            // logits = grad-gate * kernel; l in (0,5] so exp is safe w/o max-sub
            float lg[9];
            float sum = 0.f;
            #pragma unroll
            for (int k = 0; k < 9; ++k) {
                const int di = k / 3 - 1, dj = k % 3 - 1;
                float pm = m[1 + di][jc + dj];
                float g = pm - mc;
                float grad = frcp(g * g + 1.0f);
                float d0 = s0 - (float)dj;
                float d1 = s1 - (float)di;
                float kern = frcp(d0 * d0 + d1 * d1 + 0.2f);
                lg[k] = __expf(grad * kern);
                sum += lg[k];
            }
            float inv = frcp(sum);
            #pragma unroll
            for (int k = 0; k < 9; ++k) {
                const int ki = k / 3, kj = k % 3;
                float r   = (ki == 0) ? rm0 : ((ki == 2) ? rm2 : 1.f);
                float msk = (kj == 0) ? ((j < 2)  ? r * cl : r)
                          : (kj == 2) ? ((j >= 2) ? r * cr : r)
                                      : r;
                wgt[pp][k][j] = lg[k] * inv * msk;
            }
        }
    }

    // ---- Phase 2: channel loop ----
    const float* xc = x + (size_t)(b * C + cg * CPT) * (H * W);
    const float2* row0 = (const float2*)(xc + (size_t)r0 * W) + w2;
    const float2* row1 = (const float2*)(xc + (size_t)h  * W) + w2;
    const float2* row2 = (const float2*)(xc + (size_t)r2 * W) + w2;

    float* ob = out + (size_t)(b * C + cg * CPT) * (H2 * W2)
                    + (size_t)(2 * h) * W2 + 4 * w2;

    #pragma unroll 2
    for (int cc2 = 0; cc2 < CPT; ++cc2) {
        float2 v0 = row0[0];
        float2 v1 = row1[0];
        float2 v2 = row2[0];

        // e[r][c] = x[ch][h-1+r][2*w2-1+c] (edges masked via zeroed weights)
        float e[3][4];
        e[0][1] = v0.x; e[0][2] = v0.y;
        e[1][1] = v1.x; e[1][2] = v1.y;
        e[2][1] = v2.x; e[2][2] = v2.y;
        e[0][0] = __shfl_up(v0.y, 1);   e[0][3] = __shfl_down(v0.x, 1);
        e[1][0] = __shfl_up(v1.y, 1);   e[1][3] = __shfl_down(v1.x, 1);
        e[2][0] = __shfl_up(v2.y, 1);   e[2][3] = __shfl_down(v2.x, 1);

        float4 a0 = make_float4(0.f, 0.f, 0.f, 0.f);
        float4 a1 = make_float4(0.f, 0.f, 0.f, 0.f);
        #pragma unroll
        for (int k = 0; k < 9; ++k) {
            const int ki = k / 3, kj = k % 3;
            float pa = e[ki][kj];        // taps of parent col 2*w2
            float pb = e[ki][kj + 1];    // taps of parent col 2*w2+1
            a0.x += wgt[0][k][0] * pa;  a0.y += wgt[0][k][1] * pa;
            a0.z += wgt[0][k][2] * pb;  a0.w += wgt[0][k][3] * pb;
            a1.x += wgt[1][k][0] * pa;  a1.y += wgt[1][k][1] * pa;
            a1.z += wgt[1][k][2] * pb;  a1.w += wgt[1][k][3] * pb;
        }
        nt_store4(ob, a0);
        nt_store4(ob + W2, a1);

        row0 = (const float2*)((const float*)row0 + H * W);
        row1 = (const float2*)((const float*)row1 + H * W);
        row2 = (const float2*)((const float*)row2 + H * W);
        ob += (size_t)H2 * W2;
    }
}

extern "C" void kernel_launch(void* const* d_in, const int* in_sizes, int n_in,
                              void* d_out, int out_size, void* d_ws, size_t ws_size,
                              hipStream_t stream) {
    const float* x    = (const float*)d_in[0];
    const float* Woff = (const float*)d_in[1];
    const float* boff = (const float*)d_in[2];
    float* out = (float*)d_out;

    float* mean = (float*)d_ws;                 // B*H*W floats (128 KiB)

    mean_kernel<<<B * H, 1024, 0, stream>>>(x, mean);

    int mt = B * (C / CPT) * H * (W / 2);       // 262,144 threads
    carafe_fused<<<mt / 256, 256, 0, stream>>>(x, mean, Woff, boff, out);
}